// Round 2
// baseline (3111.156 us; speedup 1.0000x reference)
//
#include <hip/hip_runtime.h>

static constexpr int Nn  = 100000;
static constexpr int Ne  = 1600000;
static constexpr int Gg  = 2048;
static constexpr int Fin = 22;
static constexpr float EPSf = 1e-5f;

// ---------------- setup: deg=1, zero pooled/cnts/stats ----------------
__global__ void k_setup(float* deg, float* pooled, float* cnts, double* stats) {
    int i = blockIdx.x * blockDim.x + threadIdx.x;
    int stride = gridDim.x * blockDim.x;
    for (int j = i; j < Nn; j += stride) deg[j] = 1.0f;          // self-loop
    for (int j = i; j < Gg * 64; j += stride) pooled[j] = 0.0f;
    for (int j = i; j < Gg; j += stride) cnts[j] = 0.0f;
    for (int j = i; j < 4 * 64; j += stride) stats[j] = 0.0;     // stats1+stats2
}

// ---------------- degree (in-degree over dst) ----------------
__global__ void k_deg(const int* __restrict__ dst, float* deg) {
    int e = blockIdx.x * blockDim.x + threadIdx.x;
    if (e < Ne) atomicAdd(&deg[dst[e]], 1.0f);
}

__global__ void k_dinv(float* deg) {
    int i = blockIdx.x * blockDim.x + threadIdx.x;
    if (i < Nn) deg[i] = rsqrtf(deg[i]);
}

// ---------------- GEMM1: x[N,22] @ W1[64,22]^T -> out[N,64] ----------------
__global__ __launch_bounds__(256) void k_gemm1(const float* __restrict__ x,
                                               const float* __restrict__ W1,
                                               float* __restrict__ out) {
    __shared__ float Wl[64 * 23];   // padded stride 23
    __shared__ float Xl[4][Fin];
    int tid = threadIdx.x;
    for (int i = tid; i < 64 * Fin; i += 256) {
        int o = i / Fin, k = i % Fin;
        Wl[o * 23 + k] = W1[i];
    }
    int f = tid & 63, ln = tid >> 6;
    for (int base = blockIdx.x * 4; base < Nn; base += gridDim.x * 4) {
        __syncthreads();
        if (tid < 4 * Fin) {
            int r = tid / Fin, k = tid % Fin;
            if (base + r < Nn) Xl[r][k] = x[(base + r) * Fin + k];
        }
        __syncthreads();
        int n = base + ln;
        if (n < Nn) {
            float s = 0.f;
            #pragma unroll
            for (int k = 0; k < Fin; k++) s += Xl[ln][k] * Wl[f * 23 + k];
            out[n * 64 + f] = s;
        }
    }
}

// ---------------- GEMM2: in[N,64] @ W2[64,64]^T -> out[N,64] ----------------
__global__ __launch_bounds__(256) void k_gemm2(const float* __restrict__ xin,
                                               const float* __restrict__ W2,
                                               float* __restrict__ out) {
    __shared__ float Wl[64 * 65];   // padded stride 65 -> 2-way (free) bank alias
    __shared__ float Xl[4][64];
    int tid = threadIdx.x;
    for (int i = tid; i < 64 * 64; i += 256) {
        int o = i >> 6, k = i & 63;
        Wl[o * 65 + k] = W2[i];
    }
    int f = tid & 63, ln = tid >> 6;
    for (int base = blockIdx.x * 4; base < Nn; base += gridDim.x * 4) {
        __syncthreads();
        int n = base + ln;
        if (n < Nn) Xl[ln][f] = xin[n * 64 + f];
        __syncthreads();
        if (n < Nn) {
            float s = 0.f;
            #pragma unroll
            for (int k = 0; k < 64; k++) s += Xl[ln][k] * Wl[f * 65 + k];
            out[n * 64 + f] = s;
        }
    }
}

// ---------------- agg init: out = b + h * dinv^2 (self loop term) ----------------
__global__ void k_agg_init(const float* __restrict__ h, const float* __restrict__ dinv,
                           const float* __restrict__ b, float* __restrict__ out) {
    int idx = blockIdx.x * blockDim.x + threadIdx.x;   // over Nn*16 float4s
    if (idx >= Nn * 16) return;
    int n = idx >> 4, q = idx & 15;
    float di = dinv[n];
    float sl = di * di;
    float4 hv = ((const float4*)h)[idx];
    float4 bv = ((const float4*)b)[q];
    float4 o;
    o.x = bv.x + hv.x * sl;
    o.y = bv.y + hv.y * sl;
    o.z = bv.z + hv.z * sl;
    o.w = bv.w + hv.w * sl;
    ((float4*)out)[idx] = o;
}

// ---------------- edge scatter: out[dst] += h[src] * dinv[src]*dinv[dst] ----------------
__global__ void k_agg_edges(const int* __restrict__ src, const int* __restrict__ dst,
                            const float* __restrict__ dinv, const float* __restrict__ h,
                            float* out) {
    int idx = blockIdx.x * blockDim.x + threadIdx.x;   // Ne*16 threads, 16 per edge
    if (idx >= Ne * 16) return;
    int e = idx >> 4, q = idx & 15;
    int s = src[e], d = dst[e];
    float norm = dinv[s] * dinv[d];
    float4 hv = ((const float4*)h)[s * 16 + q];
    float* op = out + d * 64 + q * 4;
    atomicAdd(op + 0, hv.x * norm);
    atomicAdd(op + 1, hv.y * norm);
    atomicAdd(op + 2, hv.z * norm);
    atomicAdd(op + 3, hv.w * norm);
}

// ---------------- BN stats: per-feature sum & sumsq (double accum) ----------------
__global__ __launch_bounds__(256) void k_bnstats(const float* __restrict__ a, double* stats) {
    __shared__ float ssum[256], ssq[256];
    int tid = threadIdx.x;
    int f = tid & 63, ln = tid >> 6;
    float s = 0.f, q = 0.f;
    for (int n = blockIdx.x * 4 + ln; n < Nn; n += gridDim.x * 4) {
        float v = a[n * 64 + f];
        s += v;
        q += v * v;
    }
    ssum[tid] = s; ssq[tid] = q;
    __syncthreads();
    if (tid < 64) {
        s = ssum[tid] + ssum[tid + 64] + ssum[tid + 128] + ssum[tid + 192];
        q = ssq[tid] + ssq[tid + 64] + ssq[tid + 128] + ssq[tid + 192];
        atomicAdd(&stats[f], (double)s);
        atomicAdd(&stats[64 + f], (double)q);
    }
}

// ---------------- BN apply + ReLU, in place ----------------
__global__ void k_bnrelu(float* a, const double* __restrict__ stats,
                         const float* __restrict__ g, const float* __restrict__ be) {
    __shared__ float mu_s[64], sc_s[64], be_s[64];
    int tid = threadIdx.x;
    if (tid < 64) {
        double mu = stats[tid] / (double)Nn;
        double var = stats[64 + tid] / (double)Nn - mu * mu;
        float inv = rsqrtf((float)var + EPSf);
        mu_s[tid] = (float)mu;
        sc_s[tid] = inv * g[tid];
        be_s[tid] = be[tid];
    }
    __syncthreads();
    for (int idx = blockIdx.x * blockDim.x + tid; idx < Nn * 64;
         idx += gridDim.x * blockDim.x) {
        int f = idx & 63;
        float v = (a[idx] - mu_s[f]) * sc_s[f] + be_s[f];
        a[idx] = v > 0.f ? v : 0.f;
    }
}

// ---------------- pool: scatter-mean by graph ----------------
__global__ void k_pool(const float* __restrict__ a, const int* __restrict__ batch,
                       float* pooled, float* cnts) {
    int idx = blockIdx.x * blockDim.x + threadIdx.x;
    if (idx >= Nn * 64) return;
    int n = idx >> 6, f = idx & 63;
    int g = batch[n];
    atomicAdd(&pooled[g * 64 + f], a[idx]);
    if (f == 0) atomicAdd(&cnts[g], 1.0f);
}

// ---------------- final MLP: relu(p@fcw1^T+fcb1)@fcw2^T+fcb2 ----------------
__global__ void k_mlp(const float* __restrict__ pooled, const float* __restrict__ cnts,
                      const float* __restrict__ fcw1, const float* __restrict__ fcb1,
                      const float* __restrict__ fcw2, const float* __restrict__ fcb2,
                      float* __restrict__ out) {
    __shared__ float p[64];
    int g = blockIdx.x;
    int tid = threadIdx.x;   // 64
    float c = cnts[g];
    c = c < 1.f ? 1.f : c;
    p[tid] = pooled[g * 64 + tid] / c;
    __syncthreads();
    float w = 0.f;
    if (tid < 32) {
        float z = fcb1[tid];
        #pragma unroll
        for (int k = 0; k < 64; k++) z += p[k] * fcw1[tid * 64 + k];
        z = z > 0.f ? z : 0.f;
        w = z * fcw2[tid];
    }
    for (int off = 16; off; off >>= 1) w += __shfl_down(w, off);
    if (tid == 0) out[g] = w + fcb2[0];
}

extern "C" void kernel_launch(void* const* d_in, const int* in_sizes, int n_in,
                              void* d_out, int out_size, void* d_ws, size_t ws_size,
                              hipStream_t stream) {
    const float* x    = (const float*)d_in[0];
    const int* ei     = (const int*)d_in[1];
    const int* src    = ei;
    const int* dst    = ei + Ne;
    const int* batch  = (const int*)d_in[2];
    const float* W1   = (const float*)d_in[3];
    const float* b1   = (const float*)d_in[4];
    const float* g1   = (const float*)d_in[5];
    const float* be1  = (const float*)d_in[6];
    const float* W2   = (const float*)d_in[7];
    const float* b2   = (const float*)d_in[8];
    const float* g2   = (const float*)d_in[9];
    const float* be2  = (const float*)d_in[10];
    const float* fcw1 = (const float*)d_in[11];
    const float* fcb1 = (const float*)d_in[12];
    const float* fcw2 = (const float*)d_in[13];
    const float* fcb2 = (const float*)d_in[14];
    float* out = (float*)d_out;

    float* ws     = (float*)d_ws;
    float* bufA   = ws;                      // N*64
    float* bufB   = bufA + Nn * 64;          // N*64
    float* deg    = bufB + Nn * 64;          // N  (becomes dinv in place)
    float* pooled = deg + Nn;                // G*64
    float* cnts   = pooled + Gg * 64;        // G
    double* stats1 = (double*)(cnts + Gg);   // 128 doubles (8B-aligned offset)
    double* stats2 = stats1 + 128;

    k_setup<<<256, 256, 0, stream>>>(deg, pooled, cnts, stats1);
    k_deg<<<(Ne + 255) / 256, 256, 0, stream>>>(dst, deg);
    k_dinv<<<(Nn + 255) / 256, 256, 0, stream>>>(deg);

    // ---- layer 1 ----
    k_gemm1<<<1024, 256, 0, stream>>>(x, W1, bufA);
    k_agg_init<<<(Nn * 16 + 255) / 256, 256, 0, stream>>>(bufA, deg, b1, bufB);
    k_agg_edges<<<(Ne * 16 + 255) / 256, 256, 0, stream>>>(src, dst, deg, bufA, bufB);
    k_bnstats<<<512, 256, 0, stream>>>(bufB, stats1);
    k_bnrelu<<<2048, 256, 0, stream>>>(bufB, stats1, g1, be1);

    // ---- layer 2 ----
    k_gemm2<<<2048, 256, 0, stream>>>(bufB, W2, bufA);
    k_agg_init<<<(Nn * 16 + 255) / 256, 256, 0, stream>>>(bufA, deg, b2, bufB);
    k_agg_edges<<<(Ne * 16 + 255) / 256, 256, 0, stream>>>(src, dst, deg, bufA, bufB);
    k_bnstats<<<512, 256, 0, stream>>>(bufB, stats2);
    k_bnrelu<<<2048, 256, 0, stream>>>(bufB, stats2, g2, be2);

    // ---- pool + MLP ----
    k_pool<<<(Nn * 64 + 255) / 256, 256, 0, stream>>>(bufB, batch, pooled, cnts);
    k_mlp<<<Gg, 64, 0, stream>>>(pooled, cnts, fcw1, fcb1, fcw2, fcb2, out);
}

// Round 3
// 548.219 us; speedup vs baseline: 5.6750x; 5.6750x over previous
//
#include <hip/hip_runtime.h>

static constexpr int Nn  = 100000;
static constexpr int Ne  = 1600000;
static constexpr int Gg  = 2048;
static constexpr int Fin = 22;
static constexpr float EPSf = 1e-5f;
static constexpr int NBLK = (Nn + 255) / 256;   // 391 scan blocks

// ---------------- init: zero cnt + stats ----------------
__global__ void k_init(int* cnt, double* stats) {
    int i = blockIdx.x * blockDim.x + threadIdx.x;
    int stride = gridDim.x * blockDim.x;
    for (int j = i; j < Nn; j += stride) cnt[j] = 0;
    for (int j = i; j < 256; j += stride) stats[j] = 0.0;   // stats1+stats2
}

// ---------------- in-degree histogram (int atomics) ----------------
__global__ void k_count(const int* __restrict__ dst, int* cnt) {
    int e = blockIdx.x * blockDim.x + threadIdx.x;
    if (e < Ne) atomicAdd(&cnt[dst[e]], 1);
}

// ---------------- scan pass 1: per-block exclusive scan ----------------
__global__ __launch_bounds__(256) void k_scan1(const int* __restrict__ cnt,
                                               int* row_ptr, int* bsum) {
    __shared__ int sh[256];
    int t = threadIdx.x, b = blockIdx.x;
    int i = b * 256 + t;
    int v = (i < Nn) ? cnt[i] : 0;
    sh[t] = v;
    __syncthreads();
    for (int off = 1; off < 256; off <<= 1) {
        int a = (t >= off) ? sh[t - off] : 0;
        __syncthreads();
        sh[t] += a;
        __syncthreads();
    }
    if (i < Nn) row_ptr[i] = sh[t] - v;     // exclusive within block
    if (t == 255) bsum[b] = sh[255];
}

// ---------------- scan pass 2: scan the 391 block sums ----------------
__global__ __launch_bounds__(512) void k_scan2(int* bsum) {
    __shared__ int sh[512];
    int t = threadIdx.x;
    int v = (t < NBLK) ? bsum[t] : 0;
    sh[t] = v;
    __syncthreads();
    for (int off = 1; off < 512; off <<= 1) {
        int a = (t >= off) ? sh[t - off] : 0;
        __syncthreads();
        sh[t] += a;
        __syncthreads();
    }
    if (t < NBLK) bsum[t] = sh[t] - v;      // exclusive
}

// ---------------- scan pass 3: add offsets, cursor copy, dinv ----------------
__global__ __launch_bounds__(256) void k_scan3(const int* __restrict__ cnt,
                                               const int* __restrict__ bsum,
                                               int* row_ptr, int* cursor, float* dinv) {
    int i = blockIdx.x * blockDim.x + threadIdx.x;
    if (i >= Nn) return;
    int r = row_ptr[i] + bsum[blockIdx.x * 256 / 256 == blockIdx.x ? blockIdx.x : 0];
    r = row_ptr[i] + bsum[i >> 8];
    row_ptr[i] = r;
    cursor[i] = r;
    dinv[i] = rsqrtf(1.0f + (float)cnt[i]);
    if (i == 0) row_ptr[Nn] = Ne;
}

// ---------------- CSR fill: src index + precomputed norm ----------------
__global__ void k_fill(const int* __restrict__ src, const int* __restrict__ dst,
                       const float* __restrict__ dinv, int* cursor,
                       int* csr_src, float* csr_norm) {
    int e = blockIdx.x * blockDim.x + threadIdx.x;
    if (e >= Ne) return;
    int s = src[e], d = dst[e];
    int pos = atomicAdd(&cursor[d], 1);
    csr_src[pos] = s;
    csr_norm[pos] = dinv[s] * dinv[d];
}

// ---------------- GEMM1: x[N,22] @ W1[64,22]^T -> out[N,64] ----------------
__global__ __launch_bounds__(256) void k_gemm1(const float* __restrict__ x,
                                               const float* __restrict__ W1,
                                               float* __restrict__ out) {
    __shared__ float Wl[64 * 23];
    __shared__ float Xl[4][Fin];
    int tid = threadIdx.x;
    for (int i = tid; i < 64 * Fin; i += 256) {
        int o = i / Fin, k = i % Fin;
        Wl[o * 23 + k] = W1[i];
    }
    int f = tid & 63, ln = tid >> 6;
    for (int base = blockIdx.x * 4; base < Nn; base += gridDim.x * 4) {
        __syncthreads();
        if (tid < 4 * Fin) {
            int r = tid / Fin, k = tid % Fin;
            if (base + r < Nn) Xl[r][k] = x[(base + r) * Fin + k];
        }
        __syncthreads();
        int n = base + ln;
        if (n < Nn) {
            float s = 0.f;
            #pragma unroll
            for (int k = 0; k < Fin; k++) s += Xl[ln][k] * Wl[f * 23 + k];
            out[n * 64 + f] = s;
        }
    }
}

// ---------------- gather-aggregate: out[n] = b + h[n]*dinv[n]^2 + sum_e h[src]*norm ----------------
__global__ __launch_bounds__(256) void k_gather(const int* __restrict__ row_ptr,
                                                const int* __restrict__ csr_src,
                                                const float* __restrict__ csr_norm,
                                                const float* __restrict__ dinv,
                                                const float* __restrict__ h,
                                                const float* __restrict__ bias,
                                                float* __restrict__ out) {
    int idx = blockIdx.x * blockDim.x + threadIdx.x;   // Nn*16 threads
    if (idx >= Nn * 16) return;
    int n = idx >> 4, q = idx & 15;
    const float4* h4 = (const float4*)h;
    float di = dinv[n];
    float sl = di * di;
    float4 acc = ((const float4*)bias)[q];
    float4 hv = h4[n * 16 + q];
    acc.x += hv.x * sl; acc.y += hv.y * sl; acc.z += hv.z * sl; acc.w += hv.w * sl;
    int e = row_ptr[n], e1 = row_ptr[n + 1];
    for (; e + 1 < e1; e += 2) {
        int sa = csr_src[e], sb = csr_src[e + 1];
        float na = csr_norm[e], nb = csr_norm[e + 1];
        float4 va = h4[sa * 16 + q];
        float4 vb = h4[sb * 16 + q];
        acc.x += va.x * na + vb.x * nb;
        acc.y += va.y * na + vb.y * nb;
        acc.z += va.z * na + vb.z * nb;
        acc.w += va.w * na + vb.w * nb;
    }
    if (e < e1) {
        int sa = csr_src[e];
        float na = csr_norm[e];
        float4 va = h4[sa * 16 + q];
        acc.x += va.x * na; acc.y += va.y * na; acc.z += va.z * na; acc.w += va.w * na;
    }
    ((float4*)out)[n * 16 + q] = acc;
}

// ---------------- BN stats: per-feature sum & sumsq (double accum) ----------------
__global__ __launch_bounds__(256) void k_bnstats(const float* __restrict__ a, double* stats) {
    __shared__ float ssum[256], ssq[256];
    int tid = threadIdx.x;
    int f = tid & 63, ln = tid >> 6;
    float s = 0.f, q = 0.f;
    for (int n = blockIdx.x * 4 + ln; n < Nn; n += gridDim.x * 4) {
        float v = a[n * 64 + f];
        s += v;
        q += v * v;
    }
    ssum[tid] = s; ssq[tid] = q;
    __syncthreads();
    if (tid < 64) {
        s = ssum[tid] + ssum[tid + 64] + ssum[tid + 128] + ssum[tid + 192];
        q = ssq[tid] + ssq[tid + 64] + ssq[tid + 128] + ssq[tid + 192];
        atomicAdd(&stats[f], (double)s);
        atomicAdd(&stats[64 + f], (double)q);
    }
}

// ---------------- GEMM2 with fused BN1+ReLU on the X load ----------------
__global__ __launch_bounds__(256) void k_gemm2(const float* __restrict__ xin,
                                               const float* __restrict__ W2,
                                               const double* __restrict__ stats,
                                               const float* __restrict__ g,
                                               const float* __restrict__ be,
                                               float* __restrict__ out) {
    __shared__ float Wl[64 * 65];
    __shared__ float Xl[4][64];
    int tid = threadIdx.x;
    for (int i = tid; i < 64 * 64; i += 256) {
        int o = i >> 6, k = i & 63;
        Wl[o * 65 + k] = W2[i];
    }
    int f = tid & 63, ln = tid >> 6;
    double mu = stats[f] / (double)Nn;
    double var = stats[64 + f] / (double)Nn - mu * mu;
    float sc = rsqrtf((float)var + EPSf) * g[f];
    float muf = (float)mu;
    float bef = be[f];
    for (int base = blockIdx.x * 4; base < Nn; base += gridDim.x * 4) {
        __syncthreads();
        int n = base + ln;
        if (n < Nn) {
            float v = (xin[n * 64 + f] - muf) * sc + bef;
            Xl[ln][f] = v > 0.f ? v : 0.f;
        }
        __syncthreads();
        if (n < Nn) {
            float s = 0.f;
            #pragma unroll
            for (int k = 0; k < 64; k++) s += Xl[ln][k] * Wl[f * 65 + k];
            out[n * 64 + f] = s;
        }
    }
}

// ---------------- pool + BN2 + ReLU + MLP, one block (64 thr) per graph ----------------
__global__ __launch_bounds__(64) void k_poolmlp(const float* __restrict__ a,
                                                const int* __restrict__ batch,
                                                const double* __restrict__ stats,
                                                const float* __restrict__ g,
                                                const float* __restrict__ be,
                                                const float* __restrict__ fcw1,
                                                const float* __restrict__ fcb1,
                                                const float* __restrict__ fcw2,
                                                const float* __restrict__ fcb2,
                                                float* __restrict__ out) {
    __shared__ float p[64];
    int gidx = blockIdx.x;
    int tid = threadIdx.x;   // 64 = feature
    // binary search [start,end) of graph gidx in sorted batch
    int lo = 0, hi = Nn;
    while (lo < hi) { int m = (lo + hi) >> 1; if (batch[m] < gidx) lo = m + 1; else hi = m; }
    int start = lo;
    hi = Nn;
    while (lo < hi) { int m = (lo + hi) >> 1; if (batch[m] < gidx + 1) lo = m + 1; else hi = m; }
    int end = lo;
    double mu = stats[tid] / (double)Nn;
    double var = stats[64 + tid] / (double)Nn - mu * mu;
    float sc = rsqrtf((float)var + EPSf) * g[tid];
    float muf = (float)mu;
    float bef = be[tid];
    float s = 0.f;
    for (int n = start; n < end; n++) {
        float v = (a[n * 64 + tid] - muf) * sc + bef;
        s += v > 0.f ? v : 0.f;
    }
    int cnt = end - start;
    float c = cnt < 1 ? 1.f : (float)cnt;
    p[tid] = s / c;
    __syncthreads();
    float w = 0.f;
    if (tid < 32) {
        float z = fcb1[tid];
        #pragma unroll
        for (int k = 0; k < 64; k++) z += p[k] * fcw1[tid * 64 + k];
        z = z > 0.f ? z : 0.f;
        w = z * fcw2[tid];
    }
    for (int off = 16; off; off >>= 1) w += __shfl_down(w, off);
    if (tid == 0) out[gidx] = w + fcb2[0];
}

extern "C" void kernel_launch(void* const* d_in, const int* in_sizes, int n_in,
                              void* d_out, int out_size, void* d_ws, size_t ws_size,
                              hipStream_t stream) {
    const float* x    = (const float*)d_in[0];
    const int* ei     = (const int*)d_in[1];
    const int* src    = ei;
    const int* dst    = ei + Ne;
    const int* batch  = (const int*)d_in[2];
    const float* W1   = (const float*)d_in[3];
    const float* b1   = (const float*)d_in[4];
    const float* g1   = (const float*)d_in[5];
    const float* be1  = (const float*)d_in[6];
    const float* W2   = (const float*)d_in[7];
    const float* b2   = (const float*)d_in[8];
    const float* g2   = (const float*)d_in[9];
    const float* be2  = (const float*)d_in[10];
    const float* fcw1 = (const float*)d_in[11];
    const float* fcb1 = (const float*)d_in[12];
    const float* fcw2 = (const float*)d_in[13];
    const float* fcb2 = (const float*)d_in[14];
    float* out = (float*)d_out;

    // workspace layout (stats first for 8B alignment)
    double* stats1  = (double*)d_ws;             // 128
    double* stats2  = stats1 + 128;              // 128
    float*  bufA    = (float*)(stats2 + 128);    // N*64
    float*  bufB    = bufA + Nn * 64;            // N*64
    float*  dinv    = bufB + Nn * 64;            // N
    float*  csr_norm= dinv + Nn;                 // Ne
    int*    cnt     = (int*)(csr_norm + Ne);     // N
    int*    row_ptr = cnt + Nn;                  // N+1
    int*    cursor  = row_ptr + Nn + 1;          // N
    int*    csr_src = cursor + Nn;               // Ne
    int*    bsum    = csr_src + Ne;              // 512

    // ---- CSR build ----
    k_init<<<512, 256, 0, stream>>>(cnt, stats1);
    k_count<<<(Ne + 255) / 256, 256, 0, stream>>>(dst, cnt);
    k_scan1<<<NBLK, 256, 0, stream>>>(cnt, row_ptr, bsum);
    k_scan2<<<1, 512, 0, stream>>>(bsum);
    k_scan3<<<NBLK, 256, 0, stream>>>(cnt, bsum, row_ptr, cursor, dinv);
    k_fill<<<(Ne + 255) / 256, 256, 0, stream>>>(src, dst, dinv, cursor, csr_src, csr_norm);

    // ---- layer 1 ----
    k_gemm1<<<1024, 256, 0, stream>>>(x, W1, bufA);
    k_gather<<<(Nn * 16 + 255) / 256, 256, 0, stream>>>(row_ptr, csr_src, csr_norm,
                                                        dinv, bufA, b1, bufB);
    k_bnstats<<<512, 256, 0, stream>>>(bufB, stats1);

    // ---- layer 2 (BN1+ReLU fused into GEMM2 load) ----
    k_gemm2<<<2048, 256, 0, stream>>>(bufB, W2, stats1, g1, be1, bufA);
    k_gather<<<(Nn * 16 + 255) / 256, 256, 0, stream>>>(row_ptr, csr_src, csr_norm,
                                                        dinv, bufA, b2, bufB);
    k_bnstats<<<512, 256, 0, stream>>>(bufB, stats2);

    // ---- pool + BN2 + ReLU + MLP ----
    k_poolmlp<<<Gg, 64, 0, stream>>>(bufB, batch, stats2, g2, be2,
                                     fcw1, fcb1, fcw2, fcb2, out);
}

// Round 9
// 486.421 us; speedup vs baseline: 6.3960x; 1.1270x over previous
//
#include <hip/hip_runtime.h>

static constexpr int Nn  = 100000;
static constexpr int Ne  = 1600000;
static constexpr int Gg  = 2048;
static constexpr int Fin = 22;
static constexpr float EPSf = 1e-5f;
static constexpr int NBLK = (Nn + 255) / 256;   // 391 scan blocks

// ---------------- init: zero cnt + stats ----------------
__global__ void k_init(int* cnt, double* stats) {
    int i = blockIdx.x * blockDim.x + threadIdx.x;
    int stride = gridDim.x * blockDim.x;
    for (int j = i; j < Nn; j += stride) cnt[j] = 0;
    for (int j = i; j < 256; j += stride) stats[j] = 0.0;   // stats1+stats2
}

// ---------------- pad x[N,22] -> xp[N,24] (float4-friendly) ----------------
__global__ void k_pad(const float* __restrict__ x, float* __restrict__ xp) {
    int idx = blockIdx.x * blockDim.x + threadIdx.x;   // Nn*6 float4s
    if (idx >= Nn * 6) return;
    int n = idx / 6, q = idx - n * 6;
    float4 v;
    int f0 = q * 4;
    const float* xr = x + n * Fin;
    v.x = (f0 + 0 < Fin) ? xr[f0 + 0] : 0.f;
    v.y = (f0 + 1 < Fin) ? xr[f0 + 1] : 0.f;
    v.z = (f0 + 2 < Fin) ? xr[f0 + 2] : 0.f;
    v.w = (f0 + 3 < Fin) ? xr[f0 + 3] : 0.f;
    ((float4*)xp)[idx] = v;
}

// ---------------- in-degree histogram (int atomics) ----------------
__global__ void k_count(const int* __restrict__ dst, int* cnt) {
    int e = blockIdx.x * blockDim.x + threadIdx.x;
    if (e < Ne) atomicAdd(&cnt[dst[e]], 1);
}

// ---------------- scan pass 1: per-block exclusive scan ----------------
__global__ __launch_bounds__(256) void k_scan1(const int* __restrict__ cnt,
                                               int* row_ptr, int* bsum) {
    __shared__ int sh[256];
    int t = threadIdx.x, b = blockIdx.x;
    int i = b * 256 + t;
    int v = (i < Nn) ? cnt[i] : 0;
    sh[t] = v;
    __syncthreads();
    for (int off = 1; off < 256; off <<= 1) {
        int a = (t >= off) ? sh[t - off] : 0;
        __syncthreads();
        sh[t] += a;
        __syncthreads();
    }
    if (i < Nn) row_ptr[i] = sh[t] - v;     // exclusive within block
    if (t == 255) bsum[b] = sh[255];
}

// ---------------- scan pass 2: scan the 391 block sums ----------------
__global__ __launch_bounds__(512) void k_scan2(int* bsum) {
    __shared__ int sh[512];
    int t = threadIdx.x;
    int v = (t < NBLK) ? bsum[t] : 0;
    sh[t] = v;
    __syncthreads();
    for (int off = 1; off < 512; off <<= 1) {
        int a = (t >= off) ? sh[t - off] : 0;
        __syncthreads();
        sh[t] += a;
        __syncthreads();
    }
    if (t < NBLK) bsum[t] = sh[t] - v;      // exclusive
}

// ---------------- scan pass 3: add offsets, cursor copy, dinv ----------------
__global__ __launch_bounds__(256) void k_scan3(const int* __restrict__ cnt,
                                               const int* __restrict__ bsum,
                                               int* row_ptr, int* cursor, float* dinv) {
    int i = blockIdx.x * blockDim.x + threadIdx.x;
    if (i >= Nn) return;
    int r = row_ptr[i] + bsum[i >> 8];
    row_ptr[i] = r;
    cursor[i] = r;
    dinv[i] = rsqrtf(1.0f + (float)cnt[i]);
    if (i == 0) row_ptr[Nn] = Ne;
}

// ---------------- CSR fill: packed {src, norm} single 8B store ----------------
__global__ void k_fill(const int* __restrict__ src, const int* __restrict__ dst,
                       const float* __restrict__ dinv, int* cursor, int2* csr) {
    int e = blockIdx.x * blockDim.x + threadIdx.x;
    if (e >= Ne) return;
    int s = src[e], d = dst[e];
    int pos = atomicAdd(&cursor[d], 1);
    csr[pos] = make_int2(s, __float_as_int(dinv[s] * dinv[d]));
}

// ---------------- gather1: aggx[n] = xp[n]*dinv^2 + sum_e xp[src]*norm  (24 floats) ----------------
__global__ __launch_bounds__(256) void k_gather1(const int* __restrict__ row_ptr,
                                                 const int2* __restrict__ csr,
                                                 const float* __restrict__ dinv,
                                                 const float* __restrict__ xp,
                                                 float* __restrict__ outp) {
    int idx = blockIdx.x * blockDim.x + threadIdx.x;   // Nn*6 threads
    if (idx >= Nn * 6) return;
    int n = idx / 6, q = idx - n * 6;
    const float4* h4 = (const float4*)xp;
    float di = dinv[n];
    float sl = di * di;
    float4 hv = h4[n * 6 + q];
    float4 acc;
    acc.x = hv.x * sl; acc.y = hv.y * sl; acc.z = hv.z * sl; acc.w = hv.w * sl;
    int e = row_ptr[n], e1 = row_ptr[n + 1];
    for (; e + 1 < e1; e += 2) {
        int2 ea = csr[e], eb = csr[e + 1];
        float na = __int_as_float(ea.y), nb = __int_as_float(eb.y);
        float4 va = h4[ea.x * 6 + q];
        float4 vb = h4[eb.x * 6 + q];
        acc.x += va.x * na + vb.x * nb;
        acc.y += va.y * na + vb.y * nb;
        acc.z += va.z * na + vb.z * nb;
        acc.w += va.w * na + vb.w * nb;
    }
    if (e < e1) {
        int2 ea = csr[e];
        float na = __int_as_float(ea.y);
        float4 va = h4[ea.x * 6 + q];
        acc.x += va.x * na; acc.y += va.y * na; acc.z += va.z * na; acc.w += va.w * na;
    }
    ((float4*)outp)[n * 6 + q] = acc;
}

// ---------------- GEMM1: aggx[N,24(22)] @ W1[64,22]^T + b1 -> h1[N,64] ----------------
__global__ __launch_bounds__(256) void k_gemm1(const float* __restrict__ aggx,
                                               const float* __restrict__ W1,
                                               const float* __restrict__ b1,
                                               float* __restrict__ out) {
    __shared__ float Wl[64 * 23];
    __shared__ float Xl[4][24];
    int tid = threadIdx.x;
    for (int i = tid; i < 64 * Fin; i += 256) {
        int o = i / Fin, k = i % Fin;
        Wl[o * 23 + k] = W1[i];
    }
    int f = tid & 63, ln = tid >> 6;
    float bf = b1[f];
    for (int base = blockIdx.x * 4; base < Nn; base += gridDim.x * 4) {
        __syncthreads();
        if (tid < 24) {
            int r = tid / 6, q = tid - (tid / 6) * 6;
            if (base + r < Nn)
                *((float4*)&Xl[r][q * 4]) = ((const float4*)aggx)[(base + r) * 6 + q];
        }
        __syncthreads();
        int n = base + ln;
        if (n < Nn) {
            float s = bf;
            #pragma unroll
            for (int k = 0; k < Fin; k++) s += Xl[ln][k] * Wl[f * 23 + k];
            out[n * 64 + f] = s;
        }
    }
}

// ---------------- BN stats: per-feature sum & sumsq (double accum) ----------------
__global__ __launch_bounds__(256) void k_bnstats(const float* __restrict__ a, double* stats) {
    __shared__ float ssum[256], ssq[256];
    int tid = threadIdx.x;
    int f = tid & 63, ln = tid >> 6;
    float s = 0.f, q = 0.f;
    for (int n = blockIdx.x * 4 + ln; n < Nn; n += gridDim.x * 4) {
        float v = a[n * 64 + f];
        s += v;
        q += v * v;
    }
    ssum[tid] = s; ssq[tid] = q;
    __syncthreads();
    if (tid < 64) {
        s = ssum[tid] + ssum[tid + 64] + ssum[tid + 128] + ssum[tid + 192];
        q = ssq[tid] + ssq[tid + 64] + ssq[tid + 128] + ssq[tid + 192];
        atomicAdd(&stats[f], (double)s);
        atomicAdd(&stats[64 + f], (double)q);
    }
}

// ---------------- GEMM2 with fused BN1+ReLU on the X load ----------------
__global__ __launch_bounds__(256) void k_gemm2(const float* __restrict__ xin,
                                               const float* __restrict__ W2,
                                               const double* __restrict__ stats,
                                               const float* __restrict__ g,
                                               const float* __restrict__ be,
                                               float* __restrict__ out) {
    __shared__ float Wl[64 * 65];
    __shared__ float Xl[4][64];
    int tid = threadIdx.x;
    for (int i = tid; i < 64 * 64; i += 256) {
        int o = i >> 6, k = i & 63;
        Wl[o * 65 + k] = W2[i];
    }
    int f = tid & 63, ln = tid >> 6;
    double mu = stats[f] / (double)Nn;
    double var = stats[64 + f] / (double)Nn - mu * mu;
    float sc = rsqrtf((float)var + EPSf) * g[f];
    float muf = (float)mu;
    float bef = be[f];
    for (int base = blockIdx.x * 4; base < Nn; base += gridDim.x * 4) {
        __syncthreads();
        int n = base + ln;
        if (n < Nn) {
            float v = (xin[n * 64 + f] - muf) * sc + bef;
            Xl[ln][f] = v > 0.f ? v : 0.f;
        }
        __syncthreads();
        if (n < Nn) {
            float s = 0.f;
            #pragma unroll
            for (int k = 0; k < 64; k++) s += Xl[ln][k] * Wl[f * 65 + k];
            out[n * 64 + f] = s;
        }
    }
}

// ---------------- gather2: out[n] = b + h[n]*dinv^2 + sum_e h[src]*norm  (64 floats) ----------------
__global__ __launch_bounds__(256) void k_gather2(const int* __restrict__ row_ptr,
                                                 const int2* __restrict__ csr,
                                                 const float* __restrict__ dinv,
                                                 const float* __restrict__ h,
                                                 const float* __restrict__ bias,
                                                 float* __restrict__ out) {
    int idx = blockIdx.x * blockDim.x + threadIdx.x;   // Nn*16 threads
    if (idx >= Nn * 16) return;
    int n = idx >> 4, q = idx & 15;
    const float4* h4 = (const float4*)h;
    float di = dinv[n];
    float sl = di * di;
    float4 acc = ((const float4*)bias)[q];
    float4 hv = h4[n * 16 + q];
    acc.x += hv.x * sl; acc.y += hv.y * sl; acc.z += hv.z * sl; acc.w += hv.w * sl;
    int e = row_ptr[n], e1 = row_ptr[n + 1];
    for (; e + 1 < e1; e += 2) {
        int2 ea = csr[e], eb = csr[e + 1];
        float na = __int_as_float(ea.y), nb = __int_as_float(eb.y);
        float4 va = h4[ea.x * 16 + q];
        float4 vb = h4[eb.x * 16 + q];
        acc.x += va.x * na + vb.x * nb;
        acc.y += va.y * na + vb.y * nb;
        acc.z += va.z * na + vb.z * nb;
        acc.w += va.w * na + vb.w * nb;
    }
    if (e < e1) {
        int2 ea = csr[e];
        float na = __int_as_float(ea.y);
        float4 va = h4[ea.x * 16 + q];
        acc.x += va.x * na; acc.y += va.y * na; acc.z += va.z * na; acc.w += va.w * na;
    }
    ((float4*)out)[n * 16 + q] = acc;
}

// ---------------- pool + BN2 + ReLU + MLP, one block (64 thr) per graph ----------------
__global__ __launch_bounds__(64) void k_poolmlp(const float* __restrict__ a,
                                                const int* __restrict__ batch,
                                                const double* __restrict__ stats,
                                                const float* __restrict__ g,
                                                const float* __restrict__ be,
                                                const float* __restrict__ fcw1,
                                                const float* __restrict__ fcb1,
                                                const float* __restrict__ fcw2,
                                                const float* __restrict__ fcb2,
                                                float* __restrict__ out) {
    __shared__ float p[64];
    int gidx = blockIdx.x;
    int tid = threadIdx.x;   // feature
    int lo = 0, hi = Nn;
    while (lo < hi) { int m = (lo + hi) >> 1; if (batch[m] < gidx) lo = m + 1; else hi = m; }
    int start = lo;
    hi = Nn;
    while (lo < hi) { int m = (lo + hi) >> 1; if (batch[m] < gidx + 1) lo = m + 1; else hi = m; }
    int end = lo;
    double mu = stats[tid] / (double)Nn;
    double var = stats[64 + tid] / (double)Nn - mu * mu;
    float sc = rsqrtf((float)var + EPSf) * g[tid];
    float muf = (float)mu;
    float bef = be[tid];
    float s = 0.f;
    for (int n = start; n < end; n++) {
        float v = (a[n * 64 + tid] - muf) * sc + bef;
        s += v > 0.f ? v : 0.f;
    }
    int cnt = end - start;
    float c = cnt < 1 ? 1.f : (float)cnt;
    p[tid] = s / c;
    __syncthreads();
    float w = 0.f;
    if (tid < 32) {
        float z = fcb1[tid];
        #pragma unroll
        for (int k = 0; k < 64; k++) z += p[k] * fcw1[tid * 64 + k];
        z = z > 0.f ? z : 0.f;
        w = z * fcw2[tid];
    }
    for (int off = 16; off; off >>= 1) w += __shfl_down(w, off);
    if (tid == 0) out[gidx] = w + fcb2[0];
}

extern "C" void kernel_launch(void* const* d_in, const int* in_sizes, int n_in,
                              void* d_out, int out_size, void* d_ws, size_t ws_size,
                              hipStream_t stream) {
    const float* x    = (const float*)d_in[0];
    const int* ei     = (const int*)d_in[1];
    const int* src    = ei;
    const int* dst    = ei + Ne;
    const int* batch  = (const int*)d_in[2];
    const float* W1   = (const float*)d_in[3];
    const float* b1   = (const float*)d_in[4];
    const float* g1   = (const float*)d_in[5];
    const float* be1  = (const float*)d_in[6];
    const float* W2   = (const float*)d_in[7];
    const float* b2   = (const float*)d_in[8];
    const float* g2   = (const float*)d_in[9];
    const float* be2  = (const float*)d_in[10];
    const float* fcw1 = (const float*)d_in[11];
    const float* fcb1 = (const float*)d_in[12];
    const float* fcw2 = (const float*)d_in[13];
    const float* fcb2 = (const float*)d_in[14];
    float* out = (float*)d_out;

    // workspace layout (8B-aligned blocks first)
    double* stats1  = (double*)d_ws;             // 128
    double* stats2  = stats1 + 128;              // 128
    int2*   csr     = (int2*)(stats2 + 128);     // Ne packed {src, norm}
    float*  bufA    = (float*)(csr + Ne);        // N*64: xp -> h1 -> agg2
    float*  bufB    = bufA + Nn * 64;            // N*64: aggx -> z2W
    float*  dinv    = bufB + Nn * 64;            // N
    int*    cnt     = (int*)(dinv + Nn);         // N
    int*    row_ptr = cnt + Nn;                  // N+1
    int*    cursor  = row_ptr + Nn + 1;          // N
    int*    bsum    = cursor + Nn;               // 512

    // ---- CSR build + pad ----
    k_init<<<512, 256, 0, stream>>>(cnt, stats1);
    k_pad<<<(Nn * 6 + 255) / 256, 256, 0, stream>>>(x, bufA);
    k_count<<<(Ne + 255) / 256, 256, 0, stream>>>(dst, cnt);
    k_scan1<<<NBLK, 256, 0, stream>>>(cnt, row_ptr, bsum);
    k_scan2<<<1, 512, 0, stream>>>(bsum);
    k_scan3<<<NBLK, 256, 0, stream>>>(cnt, bsum, row_ptr, cursor, dinv);
    k_fill<<<(Ne + 255) / 256, 256, 0, stream>>>(src, dst, dinv, cursor, csr);

    // ---- layer 1: gather raw x (24f rows), then GEMM ----
    k_gather1<<<(Nn * 6 + 255) / 256, 256, 0, stream>>>(row_ptr, csr, dinv, bufA, bufB);
    k_gemm1<<<1024, 256, 0, stream>>>(bufB, W1, b1, bufA);
    k_bnstats<<<512, 256, 0, stream>>>(bufA, stats1);

    // ---- layer 2: GEMM (BN1+ReLU fused on load), then gather ----
    k_gemm2<<<2048, 256, 0, stream>>>(bufA, W2, stats1, g1, be1, bufB);
    k_gather2<<<(Nn * 16 + 255) / 256, 256, 0, stream>>>(row_ptr, csr, dinv, bufB, b2, bufA);
    k_bnstats<<<512, 256, 0, stream>>>(bufA, stats2);

    // ---- pool + BN2 + ReLU + MLP ----
    k_poolmlp<<<Gg, 64, 0, stream>>>(bufA, batch, stats2, g2, be2,
                                     fcw1, fcb1, fcw2, fcb2, out);
}